// Round 4
// baseline (591.535 us; speedup 1.0000x reference)
//
#include <hip/hip_runtime.h>
#include <math.h>

#define LQ_ 5440
#define NB_ 8
#define NQ_ (NB_ * LQ_)   // 43520
#define D_  256
#define NH_ 8
#define HD_ 32

typedef __attribute__((ext_vector_type(8))) short short8;
typedef __attribute__((ext_vector_type(4))) float f32x4;

__device__ __forceinline__ ushort f2bf(float f) {
    union { float f; unsigned u; } v; v.f = f;
    unsigned u = v.u;
    unsigned r = (u + 0x7FFFu + ((u >> 16) & 1u)) >> 16;
    return (ushort)r;
}
__device__ __forceinline__ float bf_lo(uint u) {
    union { unsigned u; float f; } v; v.u = u << 16; return v.f;
}
__device__ __forceinline__ float bf_hi(uint u) {
    union { unsigned u; float f; } v; v.u = u & 0xffff0000u; return v.f;
}

// ---------------------------------------------------------------------------
// Input prep: s_bf = bf16(src), q_bf = bf16(src+pos). 4 elems/thread.
// ---------------------------------------------------------------------------
__global__ void make_bf_inputs(const float* __restrict__ src, const float* __restrict__ pos,
                               ushort* __restrict__ s_bf, ushort* __restrict__ q_bf) {
    const int i = blockIdx.x * blockDim.x + threadIdx.x;
    const float4 s = ((const float4*)src)[i];
    const float4 p = ((const float4*)pos)[i];
    ushort4 a, b;
    a.x = f2bf(s.x); a.y = f2bf(s.y); a.z = f2bf(s.z); a.w = f2bf(s.w);
    b.x = f2bf(s.x + p.x); b.y = f2bf(s.y + p.y); b.z = f2bf(s.z + p.z); b.w = f2bf(s.w + p.w);
    ((ushort4*)s_bf)[i] = a;
    ((ushort4*)q_bf)[i] = b;
}

// ---------------------------------------------------------------------------
// Weight transpose + bf16 cast: W [K,N] fp32 -> Wt [N,K] bf16.
// ---------------------------------------------------------------------------
__global__ void transpose_w(const float* __restrict__ W, ushort* __restrict__ Wt, int K, int N) {
    __shared__ float tile[32][33];
    const int bx = blockIdx.x;   // n tile
    const int by = blockIdx.y;   // k tile
    const int tx = threadIdx.x;  // 0..31
    const int ty = threadIdx.y;  // 0..7
    for (int i = ty; i < 32; i += 8)
        tile[i][tx] = W[(size_t)(by * 32 + i) * N + bx * 32 + tx];
    __syncthreads();
    for (int i = ty; i < 32; i += 8)
        Wt[(size_t)(bx * 32 + i) * K + by * 32 + tx] = f2bf(tile[tx][i]);
}

// ---------------------------------------------------------------------------
// MFMA GEMM, m97-style global_load_lds staging (width=16, unpadded LDS).
// C[M,N] = A[M,K](bf16) @ Bt[N,K](bf16)^T + bias, opt ReLU.
// 128x128 tile, BK=64, 4 waves, 4x4 16x16x32 tiles/wave. fp32 or bf16 out.
// Optional second bias for column range [nsplit, N) (fused off|attn GEMM).
// ---------------------------------------------------------------------------
#define BM 128
#define BN 128
#define BKE 64

__global__ __launch_bounds__(256)
void mfma_gemm(const ushort* __restrict__ A, const ushort* __restrict__ Bt,
               const float* __restrict__ bias, const float* __restrict__ bias2, int nsplit,
               float* __restrict__ Cf, ushort* __restrict__ Cb, int N, int K, int relu) {
    __shared__ ushort lA[BM * BKE];   // 16 KB, row-major [128][64], no padding
    __shared__ ushort lB[BN * BKE];   // 16 KB
    const int t    = threadIdx.x;
    const int row0 = blockIdx.x * BM;
    const int col0 = blockIdx.y * BN;
    const int w    = t >> 6;
    const int lane = t & 63;
    const int lr   = lane & 15;
    const int quad = lane >> 4;
    const int wm   = (w >> 1) * 64;
    const int wn   = (w & 1) * 64;

    f32x4 acc[4][4];
    #pragma unroll
    for (int i = 0; i < 4; ++i)
        #pragma unroll
        for (int j = 0; j < 4; ++j)
            acc[i][j] = (f32x4){0.f, 0.f, 0.f, 0.f};

    for (int k0 = 0; k0 < K; k0 += BKE) {
        __syncthreads();
        // stage A and B tiles: 4 rounds x 256 threads x 16 B each.
        // LDS dest must be wave-uniform base + lane*16 -> idx*16 bytes, which
        // matches row-major [row][64] with row = idx>>3, seg = (idx&7)*8.
        #pragma unroll
        for (int g = 0; g < 4; ++g) {
            const int idx = g * 256 + t;
            const int row = idx >> 3;
            const int seg = (idx & 7) * 8;
            __builtin_amdgcn_global_load_lds(
                (const __attribute__((address_space(1))) unsigned int*)(A + (size_t)(row0 + row) * K + k0 + seg),
                (__attribute__((address_space(3))) unsigned int*)(lA + idx * 8), 16, 0, 0);
            __builtin_amdgcn_global_load_lds(
                (const __attribute__((address_space(1))) unsigned int*)(Bt + (size_t)(col0 + row) * K + k0 + seg),
                (__attribute__((address_space(3))) unsigned int*)(lB + idx * 8), 16, 0, 0);
        }
        __syncthreads();
        #pragma unroll
        for (int kk = 0; kk < 2; ++kk) {
            short8 af[4], bfr[4];
            #pragma unroll
            for (int i = 0; i < 4; ++i)
                af[i] = *(const short8*)(lA + (wm + i * 16 + lr) * BKE + kk * 32 + quad * 8);
            #pragma unroll
            for (int j = 0; j < 4; ++j)
                bfr[j] = *(const short8*)(lB + (wn + j * 16 + lr) * BKE + kk * 32 + quad * 8);
            #pragma unroll
            for (int i = 0; i < 4; ++i)
                #pragma unroll
                for (int j = 0; j < 4; ++j)
                    acc[i][j] = __builtin_amdgcn_mfma_f32_16x16x32_bf16(af[i], bfr[j], acc[i][j], 0, 0, 0);
        }
    }

    #pragma unroll
    for (int j = 0; j < 4; ++j) {
        const int col = col0 + wn + j * 16 + lr;
        const float bb = (bias2 && col >= nsplit) ? bias2[col - nsplit] : bias[col];
        #pragma unroll
        for (int i = 0; i < 4; ++i) {
            const int rbase = row0 + wm + i * 16 + quad * 4;
            #pragma unroll
            for (int r = 0; r < 4; ++r) {
                float v = acc[i][j][r] + bb;
                if (relu) v = fmaxf(v, 0.f);
                if (Cf) Cf[(size_t)(rbase + r) * N + col] = v;
                else    Cb[(size_t)(rbase + r) * N + col] = f2bf(v);
            }
        }
    }
}

// ---------------------------------------------------------------------------
// Fused softmax + deformable bilinear sampling. 8 queries/block, 256 thr.
// offattn fp32 (N,Lq,384): [0,256) = offsets (h,16p,2), [256,384) = logits.
// Phase 1: thread (q, h, l): softmax over its 4 points via 4-lane shfl
//          butterfly; 4 clamped corner offsets + folded weights -> LDS.
// Phase 2: thread (q, h, d4): 16 points x 4 corners, dwordx4 loads (8 bf16),
//          weights/addrs broadcast from LDS.
// ---------------------------------------------------------------------------
__global__ __launch_bounds__(256)
void msda_sample(const ushort* __restrict__ value, const float* __restrict__ offattn,
                 const float* __restrict__ refp, ushort* __restrict__ out) {
    __shared__ int   s_addr[8][8][16][4];   // 16 KB
    __shared__ float s_w[8][8][16][4];      // 16 KB

    const int t  = threadIdx.x;
    const int q  = t >> 5;          // 0..7
    const int h  = (t >> 2) & 7;    // 0..7
    const int lp = t & 3;           // phase1: level; phase2: d4
    const int nq = blockIdx.x * 8 + q;
    const int n  = nq / LQ_;

    // ---------------- phase 1 ----------------
    {
        const int l  = lp;
        const int Wl = 64 >> l;
        const int start = (16384 - (16384 >> (2 * l))) / 3;   // 0,4096,5120,5376

        const float* oa = offattn + (size_t)nq * 384;
        const float4 lg = *(const float4*)(oa + 256 + h * 16 + l * 4);
        float la[4] = {lg.x, lg.y, lg.z, lg.w};

        float m = fmaxf(fmaxf(la[0], la[1]), fmaxf(la[2], la[3]));
        m = fmaxf(m, __shfl_xor(m, 1));
        m = fmaxf(m, __shfl_xor(m, 2));
        float e[4], s = 0.f;
        #pragma unroll
        for (int j = 0; j < 4; ++j) { e[j] = __expf(la[j] - m); s += e[j]; }
        s += __shfl_xor(s, 1);
        s += __shfl_xor(s, 2);
        const float inv = 1.f / s;

        const float rx = refp[(size_t)nq * 8 + l * 2 + 0];
        const float ry = refp[(size_t)nq * 8 + l * 2 + 1];
        const float4 o01 = *(const float4*)(oa + h * 32 + l * 8);
        const float4 o23 = *(const float4*)(oa + h * 32 + l * 8 + 4);
        const float ox[4] = {o01.x, o01.z, o23.x, o23.z};
        const float oy[4] = {o01.y, o01.w, o23.y, o23.w};

        const float fw = (float)Wl;
        const int base = (n * LQ_ + start) * 256 + h * 32;

        #pragma unroll
        for (int j = 0; j < 4; ++j) {
            const float wgt = e[j] * inv;
            const float x  = (rx + ox[j] / fw) * fw - 0.5f;
            const float y  = (ry + oy[j] / fw) * fw - 0.5f;
            const float x0f = floorf(x), y0f = floorf(y);
            const int   x0 = (int)x0f, y0 = (int)y0f;
            const float wx1 = x - x0f, wy1 = y - y0f;
            const float wx0 = 1.f - wx1, wy0 = 1.f - wy1;

            const float xm0 = (x0 >= 0 && x0 < Wl) ? 1.f : 0.f;
            const float xm1 = (x0 + 1 >= 0 && x0 + 1 < Wl) ? 1.f : 0.f;
            const float ym0 = (y0 >= 0 && y0 < Wl) ? 1.f : 0.f;
            const float ym1 = (y0 + 1 >= 0 && y0 + 1 < Wl) ? 1.f : 0.f;

            const int x0c = min(max(x0, 0), Wl - 1);
            const int x1c = min(max(x0 + 1, 0), Wl - 1);
            const int y0c = min(max(y0, 0), Wl - 1);
            const int y1c = min(max(y0 + 1, 0), Wl - 1);

            const int p = l * 4 + j;
            s_addr[q][h][p][0] = base + (y0c * Wl + x0c) * 256;
            s_addr[q][h][p][1] = base + (y0c * Wl + x1c) * 256;
            s_addr[q][h][p][2] = base + (y1c * Wl + x0c) * 256;
            s_addr[q][h][p][3] = base + (y1c * Wl + x1c) * 256;
            s_w[q][h][p][0] = wgt * wy0 * wx0 * ym0 * xm0;
            s_w[q][h][p][1] = wgt * wy0 * wx1 * ym0 * xm1;
            s_w[q][h][p][2] = wgt * wy1 * wx0 * ym1 * xm0;
            s_w[q][h][p][3] = wgt * wy1 * wx1 * ym1 * xm1;
        }
    }
    __syncthreads();

    // ---------------- phase 2 ----------------
    {
        const int d4 = lp;                 // 8 bf16 = 16 B per corner
        const int de = d4 * 8;             // element offset within head row
        float acc[8];
        #pragma unroll
        for (int i = 0; i < 8; ++i) acc[i] = 0.f;

        #pragma unroll 4
        for (int p = 0; p < 16; ++p) {
            const int4   ad = *(const int4*)s_addr[q][h][p];
            const float4 wv = *(const float4*)s_w[q][h][p];
            const int   adc[4] = {ad.x, ad.y, ad.z, ad.w};
            const float wc[4]  = {wv.x, wv.y, wv.z, wv.w};
            #pragma unroll
            for (int c = 0; c < 4; ++c) {
                const uint4 v = *(const uint4*)(value + adc[c] + de);
                const float w = wc[c];
                acc[0] += w * bf_lo(v.x); acc[1] += w * bf_hi(v.x);
                acc[2] += w * bf_lo(v.y); acc[3] += w * bf_hi(v.y);
                acc[4] += w * bf_lo(v.z); acc[5] += w * bf_hi(v.z);
                acc[6] += w * bf_lo(v.w); acc[7] += w * bf_hi(v.w);
            }
        }
        uint4 o;
        o.x = (uint)f2bf(acc[0]) | ((uint)f2bf(acc[1]) << 16);
        o.y = (uint)f2bf(acc[2]) | ((uint)f2bf(acc[3]) << 16);
        o.z = (uint)f2bf(acc[4]) | ((uint)f2bf(acc[5]) << 16);
        o.w = (uint)f2bf(acc[6]) | ((uint)f2bf(acc[7]) << 16);
        *(uint4*)(out + (size_t)nq * 256 + h * 32 + de) = o;
    }
}

// ---------------------------------------------------------------------------
// x = LayerNorm(a + b); writes fp32 x and optionally bf16 x.
// ---------------------------------------------------------------------------
__global__ void add_ln(const float* __restrict__ a, const float* __restrict__ b,
                       const float* __restrict__ g, const float* __restrict__ be,
                       float* __restrict__ xf, ushort* __restrict__ xb) {
    const int row = blockIdx.x;
    const int t   = threadIdx.x;
    const size_t idx = (size_t)row * 256 + t;
    const float x = a[idx] + b[idx];

    __shared__ float sm[4];
    float v = x;
    #pragma unroll
    for (int o = 32; o > 0; o >>= 1) v += __shfl_down(v, o);
    if ((t & 63) == 0) sm[t >> 6] = v;
    __syncthreads();
    const float mu = (sm[0] + sm[1] + sm[2] + sm[3]) * (1.f / 256.f);
    __syncthreads();

    const float dx = x - mu;
    v = dx * dx;
    #pragma unroll
    for (int o = 32; o > 0; o >>= 1) v += __shfl_down(v, o);
    if ((t & 63) == 0) sm[t >> 6] = v;
    __syncthreads();
    const float var = (sm[0] + sm[1] + sm[2] + sm[3]) * (1.f / 256.f);

    const float y = dx * rsqrtf(var + 1e-5f) * g[t] + be[t];
    xf[idx] = y;
    if (xb) xb[idx] = f2bf(y);
}

// ---------------------------------------------------------------------------
extern "C" void kernel_launch(void* const* d_in, const int* in_sizes, int n_in,
                              void* d_out, int out_size, void* d_ws, size_t ws_size,
                              hipStream_t stream) {
    const float* src     = (const float*)d_in[0];
    const float* pos     = (const float*)d_in[1];
    const float* refp    = (const float*)d_in[2];
    const float* W_value = (const float*)d_in[4];
    const float* b_value = (const float*)d_in[5];
    const float* W_off   = (const float*)d_in[6];
    const float* b_off   = (const float*)d_in[7];
    const float* W_attn  = (const float*)d_in[8];
    const float* b_attn  = (const float*)d_in[9];
    const float* W_out   = (const float*)d_in[10];
    const float* b_out   = (const float*)d_in[11];
    const float* ln1g    = (const float*)d_in[12];
    const float* ln1b    = (const float*)d_in[13];
    const float* W1      = (const float*)d_in[14];
    const float* b1      = (const float*)d_in[15];
    const float* W2      = (const float*)d_in[16];
    const float* b2      = (const float*)d_in[17];
    const float* ln2g    = (const float*)d_in[18];
    const float* ln2b    = (const float*)d_in[19];
    float* out = (float*)d_out;
    char*  ws  = (char*)d_ws;

    // ---- workspace layout (byte offsets) ----
    const size_t SZ_BF = (size_t)NQ_ * 256 * 2;   // 22,282,240
    const size_t SZ_F  = (size_t)NQ_ * 256 * 4;   // 44,564,480
    ushort* s_bf    = (ushort*)(ws);                       // [0, 22.28M)
    ushort* q_bf    = (ushort*)(ws + SZ_BF);               // [22.28, 44.56)
    ushort* val_bf  = (ushort*)(ws + 2 * SZ_BF);           // [44.56, 66.85)
    float*  offattn = (float*) (ws + 3 * SZ_BF);           // [66.85, 133.69)  N*Lq*384 f32
    ushort* samp_bf = (ushort*)(ws + 3 * SZ_BF + (size_t)NQ_ * 384 * 4);  // [133.69, 155.98)
    ushort* h_bf    = (ushort*)(ws);                       // overlays [0, 89.13) — all dead by FFN1
    ushort* x_bf    = (ushort*)(ws + 3 * SZ_BF + (size_t)NQ_ * 384 * 4);  // overlays samp (dead after Wout GEMM)
    char*   wbase   = ws + 3 * SZ_BF + (size_t)NQ_ * 384 * 4 + SZ_BF;     // 155.98M
    ushort* Wv_t    = (ushort*)(wbase);                    // 128 KB
    ushort* Woa_t   = (ushort*)(wbase + 131072);           // 192 KB (384x256)
    ushort* Wout_t  = (ushort*)(wbase + 327680);           // 128 KB
    ushort* W1_t    = (ushort*)(wbase + 458752);           // 512 KB
    ushort* W2_t    = (ushort*)(wbase + 983040);           // 512 KB
    char*   fbase   = wbase + 1507328;
    float*  src2    = (float*)(fbase);                     // also ffn2
    float*  xf      = (float*)(fbase + SZ_F);              // ends ~246.6 MB

    // 0. bf16 inputs + weight transposes
    make_bf_inputs<<<dim3((NQ_ * 256 / 4) / 256), 256, 0, stream>>>(src, pos, s_bf, q_bf);
    transpose_w<<<dim3(8, 8),  dim3(32, 8), 0, stream>>>(W_value, Wv_t,   256, 256);
    transpose_w<<<dim3(8, 8),  dim3(32, 8), 0, stream>>>(W_off,   Woa_t,  256, 256);
    transpose_w<<<dim3(4, 8),  dim3(32, 8), 0, stream>>>(W_attn,  Woa_t + 256 * 256, 256, 128);
    transpose_w<<<dim3(8, 8),  dim3(32, 8), 0, stream>>>(W_out,   Wout_t, 256, 256);
    transpose_w<<<dim3(32, 8), dim3(32, 8), 0, stream>>>(W1,      W1_t,   256, 1024);
    transpose_w<<<dim3(8, 32), dim3(32, 8), 0, stream>>>(W2,      W2_t,   1024, 256);

    const int MT = NQ_ / BM;  // 340

    // 1. value = src @ Wv + bv  (bf16 out)
    mfma_gemm<<<dim3(MT, 2), 256, 0, stream>>>(s_bf, Wv_t, b_value, nullptr, 0, nullptr, val_bf, 256, 256, 0);
    // 2. offattn = q @ [Woff|Wattn] + [boff|battn]  (fp32 out, N=384)
    mfma_gemm<<<dim3(MT, 3), 256, 0, stream>>>(q_bf, Woa_t, b_off, b_attn, 256, offattn, nullptr, 384, 256, 0);
    // 3. fused softmax + sampling -> bf16
    msda_sample<<<dim3(NQ_ / 8), 256, 0, stream>>>(val_bf, offattn, refp, samp_bf);
    // 4. src2 = sampled @ Wout + bout (fp32)
    mfma_gemm<<<dim3(MT, 2), 256, 0, stream>>>(samp_bf, Wout_t, b_out, nullptr, 0, src2, nullptr, 256, 256, 0);
    // 5. x = LN(src + src2) -> fp32 + bf16
    add_ln<<<dim3(NQ_), 256, 0, stream>>>(src, src2, ln1g, ln1b, xf, x_bf);
    // 6. h = relu(x @ W1 + b1) -> bf16
    mfma_gemm<<<dim3(MT, 8), 256, 0, stream>>>(x_bf, W1_t, b1, nullptr, 0, nullptr, h_bf, 1024, 256, 1);
    // 7. ffn2 = h @ W2 + b2 -> fp32 (overlays src2)
    mfma_gemm<<<dim3(MT, 2), 256, 0, stream>>>(h_bf, W2_t, b2, nullptr, 0, src2, nullptr, 256, 1024, 0);
    // 8. out = LN(x + ffn2)
    add_ln<<<dim3(NQ_), 256, 0, stream>>>(xf, src2, ln2g, ln2b, out, nullptr);
}

// Round 5
// 586.941 us; speedup vs baseline: 1.0078x; 1.0078x over previous
//
#include <hip/hip_runtime.h>
#include <math.h>

#define LQ_ 5440
#define NB_ 8
#define NQ_ (NB_ * LQ_)   // 43520
#define D_  256
#define NH_ 8
#define HD_ 32

typedef __attribute__((ext_vector_type(8))) short short8;
typedef __attribute__((ext_vector_type(4))) float f32x4;

__device__ __forceinline__ ushort f2bf(float f) {
    union { float f; unsigned u; } v; v.f = f;
    unsigned u = v.u;
    unsigned r = (u + 0x7FFFu + ((u >> 16) & 1u)) >> 16;
    return (ushort)r;
}
__device__ __forceinline__ float bf_lo(uint u) {
    union { unsigned u; float f; } v; v.u = u << 16; return v.f;
}
__device__ __forceinline__ float bf_hi(uint u) {
    union { unsigned u; float f; } v; v.u = u & 0xffff0000u; return v.f;
}

// ---------------------------------------------------------------------------
// Input prep: s_bf = bf16(src), q_bf = bf16(src+pos). 4 elems/thread.
// ---------------------------------------------------------------------------
__global__ void make_bf_inputs(const float* __restrict__ src, const float* __restrict__ pos,
                               ushort* __restrict__ s_bf, ushort* __restrict__ q_bf) {
    const int i = blockIdx.x * blockDim.x + threadIdx.x;
    const float4 s = ((const float4*)src)[i];
    const float4 p = ((const float4*)pos)[i];
    ushort4 a, b;
    a.x = f2bf(s.x); a.y = f2bf(s.y); a.z = f2bf(s.z); a.w = f2bf(s.w);
    b.x = f2bf(s.x + p.x); b.y = f2bf(s.y + p.y); b.z = f2bf(s.z + p.z); b.w = f2bf(s.w + p.w);
    ((ushort4*)s_bf)[i] = a;
    ((ushort4*)q_bf)[i] = b;
}

// ---------------------------------------------------------------------------
// Weight transpose + bf16 cast: W [K,N] fp32 -> Wt [N,K] bf16.
// ---------------------------------------------------------------------------
__global__ void transpose_w(const float* __restrict__ W, ushort* __restrict__ Wt, int K, int N) {
    __shared__ float tile[32][33];
    const int bx = blockIdx.x;   // n tile
    const int by = blockIdx.y;   // k tile
    const int tx = threadIdx.x;  // 0..31
    const int ty = threadIdx.y;  // 0..7
    for (int i = ty; i < 32; i += 8)
        tile[i][tx] = W[(size_t)(by * 32 + i) * N + bx * 32 + tx];
    __syncthreads();
    for (int i = ty; i < 32; i += 8)
        Wt[(size_t)(bx * 32 + i) * K + by * 32 + tx] = f2bf(tile[tx][i]);
}

// ---------------------------------------------------------------------------
// MFMA GEMM, m97-style global_load_lds staging (width=16, unpadded LDS).
// C[M,N] = A[M,K](bf16) @ Bt[N,K](bf16)^T + bias, opt ReLU.
// 128x128 tile, BK=64, 4 waves, 4x4 16x16x32 tiles/wave. fp32 or bf16 out.
// Optional second bias for column range [nsplit, N) (fused off|attn GEMM).
// ---------------------------------------------------------------------------
#define BM 128
#define BN 128
#define BKE 64

__global__ __launch_bounds__(256)
void mfma_gemm(const ushort* __restrict__ A, const ushort* __restrict__ Bt,
               const float* __restrict__ bias, const float* __restrict__ bias2, int nsplit,
               float* __restrict__ Cf, ushort* __restrict__ Cb, int N, int K, int relu) {
    __shared__ ushort lA[BM * BKE];   // 16 KB, row-major [128][64], no padding
    __shared__ ushort lB[BN * BKE];   // 16 KB
    const int t    = threadIdx.x;
    const int row0 = blockIdx.x * BM;
    const int col0 = blockIdx.y * BN;
    const int w    = t >> 6;
    const int lane = t & 63;
    const int lr   = lane & 15;
    const int quad = lane >> 4;
    const int wm   = (w >> 1) * 64;
    const int wn   = (w & 1) * 64;

    f32x4 acc[4][4];
    #pragma unroll
    for (int i = 0; i < 4; ++i)
        #pragma unroll
        for (int j = 0; j < 4; ++j)
            acc[i][j] = (f32x4){0.f, 0.f, 0.f, 0.f};

    for (int k0 = 0; k0 < K; k0 += BKE) {
        __syncthreads();
        #pragma unroll
        for (int g = 0; g < 4; ++g) {
            const int idx = g * 256 + t;
            const int row = idx >> 3;
            const int seg = (idx & 7) * 8;
            __builtin_amdgcn_global_load_lds(
                (const __attribute__((address_space(1))) unsigned int*)(A + (size_t)(row0 + row) * K + k0 + seg),
                (__attribute__((address_space(3))) unsigned int*)(lA + idx * 8), 16, 0, 0);
            __builtin_amdgcn_global_load_lds(
                (const __attribute__((address_space(1))) unsigned int*)(Bt + (size_t)(col0 + row) * K + k0 + seg),
                (__attribute__((address_space(3))) unsigned int*)(lB + idx * 8), 16, 0, 0);
        }
        __syncthreads();
        #pragma unroll
        for (int kk = 0; kk < 2; ++kk) {
            short8 af[4], bfr[4];
            #pragma unroll
            for (int i = 0; i < 4; ++i)
                af[i] = *(const short8*)(lA + (wm + i * 16 + lr) * BKE + kk * 32 + quad * 8);
            #pragma unroll
            for (int j = 0; j < 4; ++j)
                bfr[j] = *(const short8*)(lB + (wn + j * 16 + lr) * BKE + kk * 32 + quad * 8);
            #pragma unroll
            for (int i = 0; i < 4; ++i)
                #pragma unroll
                for (int j = 0; j < 4; ++j)
                    acc[i][j] = __builtin_amdgcn_mfma_f32_16x16x32_bf16(af[i], bfr[j], acc[i][j], 0, 0, 0);
        }
    }

    #pragma unroll
    for (int j = 0; j < 4; ++j) {
        const int col = col0 + wn + j * 16 + lr;
        const float bb = (bias2 && col >= nsplit) ? bias2[col - nsplit] : bias[col];
        #pragma unroll
        for (int i = 0; i < 4; ++i) {
            const int rbase = row0 + wm + i * 16 + quad * 4;
            #pragma unroll
            for (int r = 0; r < 4; ++r) {
                float v = acc[i][j][r] + bb;
                if (relu) v = fmaxf(v, 0.f);
                if (Cf) Cf[(size_t)(rbase + r) * N + col] = v;
                else    Cb[(size_t)(rbase + r) * N + col] = f2bf(v);
            }
        }
    }
}

// ---------------------------------------------------------------------------
// Fused softmax + deformable bilinear sampling. 4 queries/block, 256 thr.
// offattn fp32 (N,Lq,384): [0,256) = offsets (h,16p,2), [256,384) = logits.
// Phase 1: thread (q2, h, l) [l = t&7, active l<4]: softmax over 4 points via
//          2-step shfl butterfly; 4 corner BYTE offsets + folded weights -> LDS
//          (per-(q,h) stride 272 B -> b128 reads hit all 32 banks, no conflict).
// Phase 2: thread (q2, h, d8): 16 points x 4 corners, dwordx2 loads (4 bf16),
//          saddr-form addressing (1 v_add per load).
// ---------------------------------------------------------------------------
__global__ __launch_bounds__(256)
void msda_sample(const ushort* __restrict__ value, const float* __restrict__ offattn,
                 const float* __restrict__ refp, ushort* __restrict__ out) {
    __shared__ int   s_addr[4][8][17][4];   // byte offsets; row 16 = pad
    __shared__ float s_w[4][8][17][4];

    const int t  = threadIdx.x;
    const int q2 = t >> 6;          // 0..3 (one query per wave)
    const int h  = (t >> 3) & 7;    // 0..7
    const int w3 = t & 7;           // phase1: level (if <4); phase2: d8
    const int nq = blockIdx.x * 4 + q2;
    const int n  = nq / LQ_;

    // ---------------- phase 1 ----------------
    if (w3 < 4) {
        const int l  = w3;
        const int Wl = 64 >> l;
        const int start = (16384 - (16384 >> (2 * l))) / 3;   // 0,4096,5120,5376

        const float* oa = offattn + (size_t)nq * 384;
        const float4 lg = *(const float4*)(oa + 256 + h * 16 + l * 4);
        float la[4] = {lg.x, lg.y, lg.z, lg.w};

        float m = fmaxf(fmaxf(la[0], la[1]), fmaxf(la[2], la[3]));
        m = fmaxf(m, __shfl_xor(m, 1));
        m = fmaxf(m, __shfl_xor(m, 2));
        float e[4], s = 0.f;
        #pragma unroll
        for (int j = 0; j < 4; ++j) { e[j] = __expf(la[j] - m); s += e[j]; }
        s += __shfl_xor(s, 1);
        s += __shfl_xor(s, 2);
        const float inv = 1.f / s;

        const float rx = refp[(size_t)nq * 8 + l * 2 + 0];
        const float ry = refp[(size_t)nq * 8 + l * 2 + 1];
        const float4 o01 = *(const float4*)(oa + h * 32 + l * 8);
        const float4 o23 = *(const float4*)(oa + h * 32 + l * 8 + 4);
        const float ox[4] = {o01.x, o01.z, o23.x, o23.z};
        const float oy[4] = {o01.y, o01.w, o23.y, o23.w};

        const float fw = (float)Wl;
        // byte offset base into value for (n, level-start, head)
        const int baseB = ((n * LQ_ + start) * 256 + h * 32) * 2;

        #pragma unroll
        for (int j = 0; j < 4; ++j) {
            const float wgt = e[j] * inv;
            const float x  = (rx + ox[j] / fw) * fw - 0.5f;
            const float y  = (ry + oy[j] / fw) * fw - 0.5f;
            const float x0f = floorf(x), y0f = floorf(y);
            const int   x0 = (int)x0f, y0 = (int)y0f;
            const float wx1 = x - x0f, wy1 = y - y0f;
            const float wx0 = 1.f - wx1, wy0 = 1.f - wy1;

            const float xm0 = (x0 >= 0 && x0 < Wl) ? 1.f : 0.f;
            const float xm1 = (x0 + 1 >= 0 && x0 + 1 < Wl) ? 1.f : 0.f;
            const float ym0 = (y0 >= 0 && y0 < Wl) ? 1.f : 0.f;
            const float ym1 = (y0 + 1 >= 0 && y0 + 1 < Wl) ? 1.f : 0.f;

            const int x0c = min(max(x0, 0), Wl - 1);
            const int x1c = min(max(x0 + 1, 0), Wl - 1);
            const int y0c = min(max(y0, 0), Wl - 1);
            const int y1c = min(max(y0 + 1, 0), Wl - 1);

            const int p = l * 4 + j;
            s_addr[q2][h][p][0] = baseB + (y0c * Wl + x0c) * 512;
            s_addr[q2][h][p][1] = baseB + (y0c * Wl + x1c) * 512;
            s_addr[q2][h][p][2] = baseB + (y1c * Wl + x0c) * 512;
            s_addr[q2][h][p][3] = baseB + (y1c * Wl + x1c) * 512;
            s_w[q2][h][p][0] = wgt * wy0 * wx0 * ym0 * xm0;
            s_w[q2][h][p][1] = wgt * wy0 * wx1 * ym0 * xm1;
            s_w[q2][h][p][2] = wgt * wy1 * wx0 * ym1 * xm0;
            s_w[q2][h][p][3] = wgt * wy1 * wx1 * ym1 * xm1;
        }
    }
    __syncthreads();

    // ---------------- phase 2 ----------------
    {
        const int d8  = w3;            // 4 bf16 = 8 B per corner
        const int deB = d8 * 8;        // byte offset within head row
        const char* vb = (const char*)value;

        float a0 = 0.f, a1 = 0.f, a2 = 0.f, a3 = 0.f;

        #pragma unroll 8
        for (int p = 0; p < 16; ++p) {
            const int4   ad = *(const int4*)&s_addr[q2][h][p][0];
            const float4 wv = *(const float4*)&s_w[q2][h][p][0];
            const int   adc[4] = {ad.x, ad.y, ad.z, ad.w};
            const float wc[4]  = {wv.x, wv.y, wv.z, wv.w};
            #pragma unroll
            for (int c = 0; c < 4; ++c) {
                const uint2 v = *(const uint2*)(vb + (uint)(adc[c] + deB));
                const float w = wc[c];
                a0 += w * bf_lo(v.x); a1 += w * bf_hi(v.x);
                a2 += w * bf_lo(v.y); a3 += w * bf_hi(v.y);
            }
        }
        uint2 o;
        o.x = (uint)f2bf(a0) | ((uint)f2bf(a1) << 16);
        o.y = (uint)f2bf(a2) | ((uint)f2bf(a3) << 16);
        *(uint2*)(out + (size_t)nq * 256 + h * 32 + d8 * 4) = o;
    }
}

// ---------------------------------------------------------------------------
// x = LayerNorm(a + b); writes fp32 x and optionally bf16 x.
// ---------------------------------------------------------------------------
__global__ void add_ln(const float* __restrict__ a, const float* __restrict__ b,
                       const float* __restrict__ g, const float* __restrict__ be,
                       float* __restrict__ xf, ushort* __restrict__ xb) {
    const int row = blockIdx.x;
    const int t   = threadIdx.x;
    const size_t idx = (size_t)row * 256 + t;
    const float x = a[idx] + b[idx];

    __shared__ float sm[4];
    float v = x;
    #pragma unroll
    for (int o = 32; o > 0; o >>= 1) v += __shfl_down(v, o);
    if ((t & 63) == 0) sm[t >> 6] = v;
    __syncthreads();
    const float mu = (sm[0] + sm[1] + sm[2] + sm[3]) * (1.f / 256.f);
    __syncthreads();

    const float dx = x - mu;
    v = dx * dx;
    #pragma unroll
    for (int o = 32; o > 0; o >>= 1) v += __shfl_down(v, o);
    if ((t & 63) == 0) sm[t >> 6] = v;
    __syncthreads();
    const float var = (sm[0] + sm[1] + sm[2] + sm[3]) * (1.f / 256.f);

    const float y = dx * rsqrtf(var + 1e-5f) * g[t] + be[t];
    xf[idx] = y;
    if (xb) xb[idx] = f2bf(y);
}

// ---------------------------------------------------------------------------
extern "C" void kernel_launch(void* const* d_in, const int* in_sizes, int n_in,
                              void* d_out, int out_size, void* d_ws, size_t ws_size,
                              hipStream_t stream) {
    const float* src     = (const float*)d_in[0];
    const float* pos     = (const float*)d_in[1];
    const float* refp    = (const float*)d_in[2];
    const float* W_value = (const float*)d_in[4];
    const float* b_value = (const float*)d_in[5];
    const float* W_off   = (const float*)d_in[6];
    const float* b_off   = (const float*)d_in[7];
    const float* W_attn  = (const float*)d_in[8];
    const float* b_attn  = (const float*)d_in[9];
    const float* W_out   = (const float*)d_in[10];
    const float* b_out   = (const float*)d_in[11];
    const float* ln1g    = (const float*)d_in[12];
    const float* ln1b    = (const float*)d_in[13];
    const float* W1      = (const float*)d_in[14];
    const float* b1      = (const float*)d_in[15];
    const float* W2      = (const float*)d_in[16];
    const float* b2      = (const float*)d_in[17];
    const float* ln2g    = (const float*)d_in[18];
    const float* ln2b    = (const float*)d_in[19];
    float* out = (float*)d_out;
    char*  ws  = (char*)d_ws;

    // ---- workspace layout (byte offsets) ----
    const size_t SZ_BF = (size_t)NQ_ * 256 * 2;   // 22,282,240
    const size_t SZ_F  = (size_t)NQ_ * 256 * 4;   // 44,564,480
    ushort* s_bf    = (ushort*)(ws);                       // [0, 22.28M)
    ushort* q_bf    = (ushort*)(ws + SZ_BF);               // [22.28, 44.56)
    ushort* val_bf  = (ushort*)(ws + 2 * SZ_BF);           // [44.56, 66.85)
    float*  offattn = (float*) (ws + 3 * SZ_BF);           // [66.85, 133.69)  N*Lq*384 f32
    ushort* samp_bf = (ushort*)(ws + 3 * SZ_BF + (size_t)NQ_ * 384 * 4);  // [133.69, 155.98)
    ushort* h_bf    = (ushort*)(ws);                       // overlays [0, 89.13) — all dead by FFN1
    ushort* x_bf    = (ushort*)(ws + 3 * SZ_BF + (size_t)NQ_ * 384 * 4);  // overlays samp (dead after Wout GEMM)
    char*   wbase   = ws + 3 * SZ_BF + (size_t)NQ_ * 384 * 4 + SZ_BF;     // 155.98M
    ushort* Wv_t    = (ushort*)(wbase);                    // 128 KB
    ushort* Woa_t   = (ushort*)(wbase + 131072);           // 192 KB (384x256)
    ushort* Wout_t  = (ushort*)(wbase + 327680);           // 128 KB
    ushort* W1_t    = (ushort*)(wbase + 458752);           // 512 KB
    ushort* W2_t    = (ushort*)(wbase + 983040);           // 512 KB
    char*   fbase   = wbase + 1507328;
    float*  src2    = (float*)(fbase);                     // also ffn2
    float*  xf      = (float*)(fbase + SZ_F);              // ends ~246.6 MB

    // 0. bf16 inputs + weight transposes
    make_bf_inputs<<<dim3((NQ_ * 256 / 4) / 256), 256, 0, stream>>>(src, pos, s_bf, q_bf);
    transpose_w<<<dim3(8, 8),  dim3(32, 8), 0, stream>>>(W_value, Wv_t,   256, 256);
    transpose_w<<<dim3(8, 8),  dim3(32, 8), 0, stream>>>(W_off,   Woa_t,  256, 256);
    transpose_w<<<dim3(4, 8),  dim3(32, 8), 0, stream>>>(W_attn,  Woa_t + 256 * 256, 256, 128);
    transpose_w<<<dim3(8, 8),  dim3(32, 8), 0, stream>>>(W_out,   Wout_t, 256, 256);
    transpose_w<<<dim3(32, 8), dim3(32, 8), 0, stream>>>(W1,      W1_t,   256, 1024);
    transpose_w<<<dim3(8, 32), dim3(32, 8), 0, stream>>>(W2,      W2_t,   1024, 256);

    const int MT = NQ_ / BM;  // 340

    // 1. value = src @ Wv + bv  (bf16 out)
    mfma_gemm<<<dim3(MT, 2), 256, 0, stream>>>(s_bf, Wv_t, b_value, nullptr, 0, nullptr, val_bf, 256, 256, 0);
    // 2. offattn = q @ [Woff|Wattn] + [boff|battn]  (fp32 out, N=384)
    mfma_gemm<<<dim3(MT, 3), 256, 0, stream>>>(q_bf, Woa_t, b_off, b_attn, 256, offattn, nullptr, 384, 256, 0);
    // 3. fused softmax + sampling -> bf16
    msda_sample<<<dim3(NQ_ / 4), 256, 0, stream>>>(val_bf, offattn, refp, samp_bf);
    // 4. src2 = sampled @ Wout + bout (fp32)
    mfma_gemm<<<dim3(MT, 2), 256, 0, stream>>>(samp_bf, Wout_t, b_out, nullptr, 0, src2, nullptr, 256, 256, 0);
    // 5. x = LN(src + src2) -> fp32 + bf16
    add_ln<<<dim3(NQ_), 256, 0, stream>>>(src, src2, ln1g, ln1b, xf, x_bf);
    // 6. h = relu(x @ W1 + b1) -> bf16
    mfma_gemm<<<dim3(MT, 8), 256, 0, stream>>>(x_bf, W1_t, b1, nullptr, 0, nullptr, h_bf, 1024, 256, 1);
    // 7. ffn2 = h @ W2 + b2 -> fp32 (overlays src2)
    mfma_gemm<<<dim3(MT, 2), 256, 0, stream>>>(h_bf, W2_t, b2, nullptr, 0, src2, nullptr, 256, 1024, 0);
    // 8. out = LN(x + ffn2)
    add_ln<<<dim3(NQ_), 256, 0, stream>>>(xf, src2, ln2g, ln2b, out, nullptr);
}

// Round 6
// 581.799 us; speedup vs baseline: 1.0167x; 1.0088x over previous
//
#include <hip/hip_runtime.h>
#include <math.h>

#define LQ_ 5440
#define NB_ 8
#define NQ_ (NB_ * LQ_)   // 43520
#define D_  256
#define NH_ 8
#define HD_ 32

typedef __attribute__((ext_vector_type(8))) short short8;
typedef __attribute__((ext_vector_type(4))) float f32x4;

__device__ __forceinline__ ushort f2bf(float f) {
    union { float f; unsigned u; } v; v.f = f;
    unsigned u = v.u;
    unsigned r = (u + 0x7FFFu + ((u >> 16) & 1u)) >> 16;
    return (ushort)r;
}
__device__ __forceinline__ float bf_lo(uint u) {
    union { unsigned u; float f; } v; v.u = u << 16; return v.f;
}
__device__ __forceinline__ float bf_hi(uint u) {
    union { unsigned u; float f; } v; v.u = u & 0xffff0000u; return v.f;
}

// ---------------------------------------------------------------------------
// Input prep: s_bf = bf16(src), q_bf = bf16(src+pos). 4 elems/thread.
// ---------------------------------------------------------------------------
__global__ void make_bf_inputs(const float* __restrict__ src, const float* __restrict__ pos,
                               ushort* __restrict__ s_bf, ushort* __restrict__ q_bf) {
    const int i = blockIdx.x * blockDim.x + threadIdx.x;
    const float4 s = ((const float4*)src)[i];
    const float4 p = ((const float4*)pos)[i];
    ushort4 a, b;
    a.x = f2bf(s.x); a.y = f2bf(s.y); a.z = f2bf(s.z); a.w = f2bf(s.w);
    b.x = f2bf(s.x + p.x); b.y = f2bf(s.y + p.y); b.z = f2bf(s.z + p.z); b.w = f2bf(s.w + p.w);
    ((ushort4*)s_bf)[i] = a;
    ((ushort4*)q_bf)[i] = b;
}

// ---------------------------------------------------------------------------
// Weight transpose + bf16 cast: W [K,N] fp32 -> Wt [N,K] bf16.
// ---------------------------------------------------------------------------
__global__ void transpose_w(const float* __restrict__ W, ushort* __restrict__ Wt, int K, int N) {
    __shared__ float tile[32][33];
    const int bx = blockIdx.x;
    const int by = blockIdx.y;
    const int tx = threadIdx.x;
    const int ty = threadIdx.y;
    for (int i = ty; i < 32; i += 8)
        tile[i][tx] = W[(size_t)(by * 32 + i) * N + bx * 32 + tx];
    __syncthreads();
    for (int i = ty; i < 32; i += 8)
        Wt[(size_t)(bx * 32 + i) * K + by * 32 + tx] = f2bf(tile[tx][i]);
}

// ---------------------------------------------------------------------------
// MFMA GEMM with LDS-staged vectorized epilogue.
// C[M,N] = A[M,K](bf16) @ Bt[N,K](bf16)^T + bias, opt ReLU.
// 128x128 tile, BK=64, 4 waves, 4x4 16x16x32 tiles/wave.
// mode 0: fp32 out (Cf). mode 1: bf16 out (Cb). mode 2: bf16 out scattered to
// value layout (N, NH, Lq, HD).
// ---------------------------------------------------------------------------
#define BM 128
#define BN 128
#define BKE 64

__global__ __launch_bounds__(256)
void mfma_gemm(const ushort* __restrict__ A, const ushort* __restrict__ Bt,
               const float* __restrict__ bias, const float* __restrict__ bias2, int nsplit,
               float* __restrict__ Cf, ushort* __restrict__ Cb, int N, int K,
               int relu, int mode) {
    __shared__ ushort lmem[2 * BM * BKE];   // 32 KB; staging + epilogue reuse
    ushort* lA = lmem;
    ushort* lB = lmem + BM * BKE;
    float*  lC = (float*)lmem;              // epilogue: 32 x 130 fp32

    const int t    = threadIdx.x;
    const int row0 = blockIdx.x * BM;
    const int col0 = blockIdx.y * BN;
    const int w    = t >> 6;
    const int lane = t & 63;
    const int lr   = lane & 15;
    const int quad = lane >> 4;
    const int wm   = (w >> 1) * 64;
    const int wn   = (w & 1) * 64;

    f32x4 acc[4][4];
    #pragma unroll
    for (int i = 0; i < 4; ++i)
        #pragma unroll
        for (int j = 0; j < 4; ++j)
            acc[i][j] = (f32x4){0.f, 0.f, 0.f, 0.f};

    for (int k0 = 0; k0 < K; k0 += BKE) {
        __syncthreads();
        #pragma unroll
        for (int g = 0; g < 4; ++g) {
            const int idx = g * 256 + t;
            const int row = idx >> 3;
            const int seg = (idx & 7) * 8;
            __builtin_amdgcn_global_load_lds(
                (const __attribute__((address_space(1))) unsigned int*)(A + (size_t)(row0 + row) * K + k0 + seg),
                (__attribute__((address_space(3))) unsigned int*)(lA + idx * 8), 16, 0, 0);
            __builtin_amdgcn_global_load_lds(
                (const __attribute__((address_space(1))) unsigned int*)(Bt + (size_t)(col0 + row) * K + k0 + seg),
                (__attribute__((address_space(3))) unsigned int*)(lB + idx * 8), 16, 0, 0);
        }
        __syncthreads();
        #pragma unroll
        for (int kk = 0; kk < 2; ++kk) {
            short8 af[4], bfr[4];
            #pragma unroll
            for (int i = 0; i < 4; ++i)
                af[i] = *(const short8*)(lA + (wm + i * 16 + lr) * BKE + kk * 32 + quad * 8);
            #pragma unroll
            for (int j = 0; j < 4; ++j)
                bfr[j] = *(const short8*)(lB + (wn + j * 16 + lr) * BKE + kk * 32 + quad * 8);
            #pragma unroll
            for (int i = 0; i < 4; ++i)
                #pragma unroll
                for (int j = 0; j < 4; ++j)
                    acc[i][j] = __builtin_amdgcn_mfma_f32_16x16x32_bf16(af[i], bfr[j], acc[i][j], 0, 0, 0);
        }
    }

    // ---- epilogue: 4 chunks of 32 rows, staged through LDS ----
    const int rr = t >> 3;          // 0..31
    const int cs = (t & 7) * 16;    // col segment start

    for (int c = 0; c < 4; ++c) {
        __syncthreads();
        if ((wm == 0) == (c < 2)) {
            const int i0 = (c & 1) * 2;
            #pragma unroll
            for (int ii = 0; ii < 2; ++ii) {
                #pragma unroll
                for (int j = 0; j < 4; ++j) {
                    const int col = col0 + wn + j * 16 + lr;
                    const float bb = (bias2 && col >= nsplit) ? bias2[col - nsplit] : bias[col];
                    const int lrow = ii * 16 + quad * 4;
                    #pragma unroll
                    for (int r = 0; r < 4; ++r) {
                        float v = acc[i0 + ii][j][r] + bb;
                        if (relu) v = fmaxf(v, 0.f);
                        lC[(lrow + r) * 130 + wn + j * 16 + lr] = v;
                    }
                }
            }
        }
        __syncthreads();

        const int grow = row0 + c * 32 + rr;
        float4 v4[4];
        #pragma unroll
        for (int k = 0; k < 4; ++k)
            v4[k] = *(const float4*)&lC[rr * 130 + cs + k * 4];

        if (mode == 0) {
            float* dst = Cf + (size_t)grow * N + col0 + cs;
            #pragma unroll
            for (int k = 0; k < 4; ++k) ((float4*)dst)[k] = v4[k];
        } else {
            uint u[8];
            #pragma unroll
            for (int k = 0; k < 4; ++k) {
                u[2 * k]     = (uint)f2bf(v4[k].x) | ((uint)f2bf(v4[k].y) << 16);
                u[2 * k + 1] = (uint)f2bf(v4[k].z) | ((uint)f2bf(v4[k].w) << 16);
            }
            uint4 o0 = {u[0], u[1], u[2], u[3]};
            uint4 o1 = {u[4], u[5], u[6], u[7]};
            if (mode == 1) {
                ushort* dst = Cb + (size_t)grow * N + col0 + cs;
                ((uint4*)dst)[0] = o0;
                ((uint4*)dst)[1] = o1;
            } else {
                const int nn = grow / LQ_;
                const int lq = grow - nn * LQ_;
                const int gc = col0 + cs;
                const int hh = gc >> 5;
                ushort* dst = Cb + (((size_t)(nn * 8 + hh) * LQ_ + lq) << 5) + (gc & 31);
                ((uint4*)dst)[0] = o0;
                ((uint4*)dst)[1] = o1;
            }
        }
    }
}

// ---------------------------------------------------------------------------
// Fused softmax + deformable bilinear sampling, paired-corner loads.
// value layout: (N, NH, Lq, HD) bf16 — x-adjacent corners are contiguous
// 128 B, loaded by 8 lanes (slot = x-corner, doq = d-octet) with dwordx4.
// Block = 256 thr = 4 waves = 4 queries.
// Phase 1 (lanes w3<4): per (q,h,l): softmax (shfl), per point: top/bottom
//   row byte-addresses at xbase=clamp(x0,0,W-2) + 4 slot-folded weights.
// Phase 2: per (q,h,slot,doq): 16 points x 2 row loads, slot-select weight,
//   final shfl_xor(4) slot reduction; slot-0 lanes store uint4.
// ---------------------------------------------------------------------------
__global__ __launch_bounds__(256)
void msda_sample(const ushort* __restrict__ value, const float* __restrict__ offattn,
                 const float* __restrict__ refp, ushort* __restrict__ out) {
    __shared__ int   s_ad[4][8][17][2];
    __shared__ float s_w[4][8][17][4];

    const int t    = threadIdx.x;
    const int q2   = t >> 6;
    const int lane = t & 63;
    const int h    = (lane >> 3) & 7;
    const int w3   = lane & 7;
    const int nq   = blockIdx.x * 4 + q2;
    const int n    = nq / LQ_;

    // ---------------- phase 1 ----------------
    if (w3 < 4) {
        const int l  = w3;
        const int Wl = 64 >> l;
        const int start = (16384 - (16384 >> (2 * l))) / 3;   // 0,4096,5120,5376

        const float* oa = offattn + (size_t)nq * 384;
        const float4 lg = *(const float4*)(oa + 256 + h * 16 + l * 4);
        float la[4] = {lg.x, lg.y, lg.z, lg.w};

        float m = fmaxf(fmaxf(la[0], la[1]), fmaxf(la[2], la[3]));
        m = fmaxf(m, __shfl_xor(m, 1));
        m = fmaxf(m, __shfl_xor(m, 2));
        float e[4], s = 0.f;
        #pragma unroll
        for (int j = 0; j < 4; ++j) { e[j] = __expf(la[j] - m); s += e[j]; }
        s += __shfl_xor(s, 1);
        s += __shfl_xor(s, 2);
        const float inv = 1.f / s;

        const float rx = refp[(size_t)nq * 8 + l * 2 + 0];
        const float ry = refp[(size_t)nq * 8 + l * 2 + 1];
        const float4 o01 = *(const float4*)(oa + h * 32 + l * 8);
        const float4 o23 = *(const float4*)(oa + h * 32 + l * 8 + 4);
        const float ox[4] = {o01.x, o01.z, o23.x, o23.z};
        const float oy[4] = {o01.y, o01.w, o23.y, o23.w};

        const float fw = (float)Wl;
        // byte base of (n, h, level) in value (N, NH, Lq, HD) bf16
        const int baseB = ((n * 8 + h) * LQ_ + start) * 64;

        #pragma unroll
        for (int j = 0; j < 4; ++j) {
            const float wgt = e[j] * inv;
            const float x  = (rx + ox[j] / fw) * fw - 0.5f;
            const float y  = (ry + oy[j] / fw) * fw - 0.5f;
            const float x0f = floorf(x), y0f = floorf(y);
            const int   x0 = (int)x0f, y0 = (int)y0f;
            const float wx1 = x - x0f, wy1 = y - y0f;
            const float wx0 = 1.f - wx1, wy0 = 1.f - wy1;

            const float c0 = (x0 >= 0 && x0 < Wl) ? wx0 : 0.f;
            const float c1 = (x0 + 1 >= 0 && x0 + 1 < Wl) ? wx1 : 0.f;
            float wy0m = (y0 >= 0 && y0 < Wl) ? wy0 : 0.f;
            float wy1m = (y0 + 1 >= 0 && y0 + 1 < Wl) ? wy1 : 0.f;

            const int xbase = min(max(x0, 0), Wl - 2);
            float ws0, ws1;
            if (x0 == xbase)           { ws0 = c0;  ws1 = c1; }
            else if (x0 == xbase + 1)  { ws0 = 0.f; ws1 = c0; }   // x0 = W-1
            else if (x0 + 1 == xbase)  { ws0 = c1;  ws1 = 0.f; }  // x0 = -1
            else                       { ws0 = 0.f; ws1 = 0.f; }

            const int y0c = min(max(y0, 0), Wl - 1);
            const int y1c = min(max(y0 + 1, 0), Wl - 1);

            const int p = l * 4 + j;
            s_ad[q2][h][p][0] = baseB + (y0c * Wl + xbase) * 64;
            s_ad[q2][h][p][1] = baseB + (y1c * Wl + xbase) * 64;
            s_w[q2][h][p][0] = wgt * wy0m * ws0;
            s_w[q2][h][p][1] = wgt * wy0m * ws1;
            s_w[q2][h][p][2] = wgt * wy1m * ws0;
            s_w[q2][h][p][3] = wgt * wy1m * ws1;
        }
    }
    __syncthreads();

    // ---------------- phase 2 ----------------
    {
        const int slot = (lane >> 2) & 1;
        const int doq  = lane & 3;
        const int lb   = (lane & 7) * 16;   // byte offset within 128 B pair
        const char* vb = (const char*)value;

        float a[8];
        #pragma unroll
        for (int k = 0; k < 8; ++k) a[k] = 0.f;

        #pragma unroll 8
        for (int p = 0; p < 16; ++p) {
            const int2   ad = *(const int2*)&s_ad[q2][h][p][0];
            const float4 wv = *(const float4*)&s_w[q2][h][p][0];
            const float wT = slot ? wv.y : wv.x;
            const float wB = slot ? wv.w : wv.z;
            const uint4 vT = *(const uint4*)(vb + (uint)(ad.x + lb));
            const uint4 vB = *(const uint4*)(vb + (uint)(ad.y + lb));
            a[0] += wT * bf_lo(vT.x); a[1] += wT * bf_hi(vT.x);
            a[2] += wT * bf_lo(vT.y); a[3] += wT * bf_hi(vT.y);
            a[4] += wT * bf_lo(vT.z); a[5] += wT * bf_hi(vT.z);
            a[6] += wT * bf_lo(vT.w); a[7] += wT * bf_hi(vT.w);
            a[0] += wB * bf_lo(vB.x); a[1] += wB * bf_hi(vB.x);
            a[2] += wB * bf_lo(vB.y); a[3] += wB * bf_hi(vB.y);
            a[4] += wB * bf_lo(vB.z); a[5] += wB * bf_hi(vB.z);
            a[6] += wB * bf_lo(vB.w); a[7] += wB * bf_hi(vB.w);
        }
        #pragma unroll
        for (int k = 0; k < 8; ++k) a[k] += __shfl_xor(a[k], 4);

        if (slot == 0) {
            uint4 o;
            o.x = (uint)f2bf(a[0]) | ((uint)f2bf(a[1]) << 16);
            o.y = (uint)f2bf(a[2]) | ((uint)f2bf(a[3]) << 16);
            o.z = (uint)f2bf(a[4]) | ((uint)f2bf(a[5]) << 16);
            o.w = (uint)f2bf(a[6]) | ((uint)f2bf(a[7]) << 16);
            *(uint4*)(out + (size_t)nq * 256 + h * 32 + doq * 8) = o;
        }
    }
}

// ---------------------------------------------------------------------------
// x = LayerNorm(a + b); writes fp32 x and optionally bf16 x.
// ---------------------------------------------------------------------------
__global__ void add_ln(const float* __restrict__ a, const float* __restrict__ b,
                       const float* __restrict__ g, const float* __restrict__ be,
                       float* __restrict__ xf, ushort* __restrict__ xb) {
    const int row = blockIdx.x;
    const int t   = threadIdx.x;
    const size_t idx = (size_t)row * 256 + t;
    const float x = a[idx] + b[idx];

    __shared__ float sm[4];
    float v = x;
    #pragma unroll
    for (int o = 32; o > 0; o >>= 1) v += __shfl_down(v, o);
    if ((t & 63) == 0) sm[t >> 6] = v;
    __syncthreads();
    const float mu = (sm[0] + sm[1] + sm[2] + sm[3]) * (1.f / 256.f);
    __syncthreads();

    const float dx = x - mu;
    v = dx * dx;
    #pragma unroll
    for (int o = 32; o > 0; o >>= 1) v += __shfl_down(v, o);
    if ((t & 63) == 0) sm[t >> 6] = v;
    __syncthreads();
    const float var = (sm[0] + sm[1] + sm[2] + sm[3]) * (1.f / 256.f);

    const float y = dx * rsqrtf(var + 1e-5f) * g[t] + be[t];
    xf[idx] = y;
    if (xb) xb[idx] = f2bf(y);
}

// ---------------------------------------------------------------------------
extern "C" void kernel_launch(void* const* d_in, const int* in_sizes, int n_in,
                              void* d_out, int out_size, void* d_ws, size_t ws_size,
                              hipStream_t stream) {
    const float* src     = (const float*)d_in[0];
    const float* pos     = (const float*)d_in[1];
    const float* refp    = (const float*)d_in[2];
    const float* W_value = (const float*)d_in[4];
    const float* b_value = (const float*)d_in[5];
    const float* W_off   = (const float*)d_in[6];
    const float* b_off   = (const float*)d_in[7];
    const float* W_attn  = (const float*)d_in[8];
    const float* b_attn  = (const float*)d_in[9];
    const float* W_out   = (const float*)d_in[10];
    const float* b_out   = (const float*)d_in[11];
    const float* ln1g    = (const float*)d_in[12];
    const float* ln1b    = (const float*)d_in[13];
    const float* W1      = (const float*)d_in[14];
    const float* b1      = (const float*)d_in[15];
    const float* W2      = (const float*)d_in[16];
    const float* b2      = (const float*)d_in[17];
    const float* ln2g    = (const float*)d_in[18];
    const float* ln2b    = (const float*)d_in[19];
    float* out = (float*)d_out;
    char*  ws  = (char*)d_ws;

    // ---- workspace layout (byte offsets) ----
    const size_t SZ_BF = (size_t)NQ_ * 256 * 2;   // 22,282,240
    const size_t SZ_F  = (size_t)NQ_ * 256 * 4;   // 44,564,480
    ushort* s_bf    = (ushort*)(ws);
    ushort* q_bf    = (ushort*)(ws + SZ_BF);
    ushort* val_bf  = (ushort*)(ws + 2 * SZ_BF);           // value, (N,NH,Lq,HD) layout
    float*  offattn = (float*) (ws + 3 * SZ_BF);           // N*Lq*384 f32
    ushort* samp_bf = (ushort*)(ws + 3 * SZ_BF + (size_t)NQ_ * 384 * 4);
    ushort* h_bf    = (ushort*)(ws);                       // overlays s/q/val (dead by FFN1)
    ushort* x_bf    = (ushort*)(ws + 3 * SZ_BF + (size_t)NQ_ * 384 * 4);  // overlays samp
    char*   wbase   = ws + 3 * SZ_BF + (size_t)NQ_ * 384 * 4 + SZ_BF;
    ushort* Wv_t    = (ushort*)(wbase);
    ushort* Woa_t   = (ushort*)(wbase + 131072);
    ushort* Wout_t  = (ushort*)(wbase + 327680);
    ushort* W1_t    = (ushort*)(wbase + 458752);
    ushort* W2_t    = (ushort*)(wbase + 983040);
    char*   fbase   = wbase + 1507328;
    float*  src2    = (float*)(fbase);                     // also ffn2
    float*  xf      = (float*)(fbase + SZ_F);

    // 0. bf16 inputs + weight transposes
    make_bf_inputs<<<dim3((NQ_ * 256 / 4) / 256), 256, 0, stream>>>(src, pos, s_bf, q_bf);
    transpose_w<<<dim3(8, 8),  dim3(32, 8), 0, stream>>>(W_value, Wv_t,   256, 256);
    transpose_w<<<dim3(8, 8),  dim3(32, 8), 0, stream>>>(W_off,   Woa_t,  256, 256);
    transpose_w<<<dim3(4, 8),  dim3(32, 8), 0, stream>>>(W_attn,  Woa_t + 256 * 256, 256, 128);
    transpose_w<<<dim3(8, 8),  dim3(32, 8), 0, stream>>>(W_out,   Wout_t, 256, 256);
    transpose_w<<<dim3(32, 8), dim3(32, 8), 0, stream>>>(W1,      W1_t,   256, 1024);
    transpose_w<<<dim3(8, 32), dim3(32, 8), 0, stream>>>(W2,      W2_t,   1024, 256);

    const int MT = NQ_ / BM;  // 340

    // 1. value = src @ Wv + bv  -> bf16, scattered to (N,NH,Lq,HD)
    mfma_gemm<<<dim3(MT, 2), 256, 0, stream>>>(s_bf, Wv_t, b_value, nullptr, 0, nullptr, val_bf, 256, 256, 0, 2);
    // 2. offattn = q @ [Woff|Wattn]  (fp32, N=384)
    mfma_gemm<<<dim3(MT, 3), 256, 0, stream>>>(q_bf, Woa_t, b_off, b_attn, 256, offattn, nullptr, 384, 256, 0, 0);
    // 3. fused softmax + sampling -> bf16 (N,Lq,NH,HD)
    msda_sample<<<dim3(NQ_ / 4), 256, 0, stream>>>(val_bf, offattn, refp, samp_bf);
    // 4. src2 = sampled @ Wout + bout (fp32)
    mfma_gemm<<<dim3(MT, 2), 256, 0, stream>>>(samp_bf, Wout_t, b_out, nullptr, 0, src2, nullptr, 256, 256, 0, 0);
    // 5. x = LN(src + src2) -> fp32 + bf16
    add_ln<<<dim3(NQ_), 256, 0, stream>>>(src, src2, ln1g, ln1b, xf, x_bf);
    // 6. h = relu(x @ W1 + b1) -> bf16
    mfma_gemm<<<dim3(MT, 8), 256, 0, stream>>>(x_bf, W1_t, b1, nullptr, 0, nullptr, h_bf, 1024, 256, 1, 1);
    // 7. ffn2 = h @ W2 + b2 -> fp32
    mfma_gemm<<<dim3(MT, 2), 256, 0, stream>>>(h_bf, W2_t, b2, nullptr, 0, src2, nullptr, 256, 1024, 0, 0);
    // 8. out = LN(x + ffn2)
    add_ln<<<dim3(NQ_), 256, 0, stream>>>(xf, src2, ln2g, ln2b, out, nullptr);
}